// Round 23
// baseline (420.308 us; speedup 1.0000x reference)
//
#include <hip/hip_runtime.h>
#include <hip/hip_bf16.h>
#include <hip/hip_fp8.h>
#include <math.h>

typedef __attribute__((ext_vector_type(4))) float f32x4;

#define NB 4096
#define ND 1024
#define INV_T 14.2857142857142857f   // 1/0.07

__device__ inline float fp82f(unsigned char b) {
    __hip_fp8_e4m3 h; h.__x = b;
    return (float)h;
}
__device__ inline void gload16(const void* g, void* l) {
    __builtin_amdgcn_global_load_lds(
        (const __attribute__((address_space(1))) void*)g,
        (__attribute__((address_space(3))) void*)l, 16, 0, 0);
}

// ---------------- kernel 0: L2-normalize rows, cast to fp8 e4m3 -------------
__global__ __launch_bounds__(256) void norm_kernel(
        const float* __restrict__ M, const float* __restrict__ P,
        unsigned char* __restrict__ Mf, unsigned char* __restrict__ Pf) {
    int row = blockIdx.x & (NB - 1);
    const float* src = (blockIdx.x < NB) ? M : P;
    unsigned char* dst = (blockIdx.x < NB) ? Mf : Pf;
    int tid = threadIdx.x;
    float4 v = ((const float4*)(src + (size_t)row * ND))[tid];
    float ss = v.x * v.x + v.y * v.y + v.z * v.z + v.w * v.w;
    for (int off = 32; off; off >>= 1) ss += __shfl_down(ss, off);
    __shared__ float red[4];
    int lane = tid & 63, w = tid >> 6;
    if (lane == 0) red[w] = ss;
    __syncthreads();
    float rn = rsqrtf(red[0] + red[1] + red[2] + red[3]);
    int p = __builtin_amdgcn_cvt_pk_fp8_f32(v.x * rn, v.y * rn, 0, false);
    p = __builtin_amdgcn_cvt_pk_fp8_f32(v.z * rn, v.w * rn, p, true);
    ((int*)dst)[row * 256 + tid] = p;
}

// ---------------- kernel 1: per-row mask codes ------------------------------
__global__ __launch_bounds__(256) void key_kernel(
        const int* __restrict__ labels, const int* __restrict__ sm,
        const int* __restrict__ sp, int* __restrict__ code) {
    int i = blockIdx.x * 256 + threadIdx.x;
    if (i < NB) {
        int l = labels[i];
        code[i] = (l == 0) ? 0x40000000 : (1 + l + (sm[i] << 8) + (sp[i] << 16));
    }
}

// ------- kernel 2: fused row-sum + normalized masked weight matrix (fp8) ----
__global__ __launch_bounds__(256) void rowsumw_kernel(
        const float* __restrict__ cs, const int* __restrict__ code,
        unsigned char* __restrict__ W, float* __restrict__ flag) {
    int i = blockIdx.x;
    int ci = code[i];
    int tid = threadIdx.x;
    const float4* row = (const float4*)(cs + (size_t)i * NB);
    const int4* c4 = (const int4*)code;
    float4 v[4];
    int4 cj[4];
    float s = 0.f;
#pragma unroll
    for (int k = 0; k < 4; ++k) {
        int t = tid + k * 256;
        v[k] = row[t];
        cj[k] = c4[t];
        int j = t * 4;
        if (cj[k].x == ci && j + 0 != i) s += v[k].x;
        if (cj[k].y == ci && j + 1 != i) s += v[k].y;
        if (cj[k].z == ci && j + 2 != i) s += v[k].z;
        if (cj[k].w == ci && j + 3 != i) s += v[k].w;
    }
    for (int off = 1; off < 64; off <<= 1) s += __shfl_xor(s, off);
    __shared__ float red[4];
    int lane = tid & 63, w = tid >> 6;
    if (lane == 0) red[w] = s;
    __syncthreads();
    float tot = red[0] + red[1] + red[2] + red[3];
    float inv = (tot > 0.f) ? 1.f / tot : 0.f;
#pragma unroll
    for (int k = 0; k < 4; ++k) {
        int t = tid + k * 256;
        int j = t * 4;
        float f0 = (cj[k].x == ci && j + 0 != i) ? v[k].x * inv : 0.f;
        float f1 = (cj[k].y == ci && j + 1 != i) ? v[k].y * inv : 0.f;
        float f2 = (cj[k].z == ci && j + 2 != i) ? v[k].z * inv : 0.f;
        float f3 = (cj[k].w == ci && j + 3 != i) ? v[k].w * inv : 0.f;
        int p = __builtin_amdgcn_cvt_pk_fp8_f32(f0, f1, 0, false);
        p = __builtin_amdgcn_cvt_pk_fp8_f32(f2, f3, p, true);
        ((int*)W)[((size_t)i * NB + j) >> 2] = p;
    }
    if (tid == 0) flag[i] = (tot > 0.f) ? 1.f : 0.f;
}

// ---------------- kernel 3: 1-WAVE barrier-free fp8 128x128-tile GEMM -------
// 2080 blocks (XCD-chunked, 2080 = 8*260), 64 threads = ONE wave:
//   b < 1024: cross S1 = Mf Pf^T, 4x4-supertiled 32x32 grid (1MB/supertile).
//   b >= 1024: symmetric (Mf then Pf), upper-tri 528 each.
// THE cell the frontier analysis points at: barrier-free self-paced staging
// (92 cy/KB measured, R19-21) x 128^2 arithmetic intensity (0.53 GB staged,
// half of R19-21). acc[8][8] = 256 AGPR requires the 512-reg/lane budget of
// 1 wave/SIMD -> __launch_bounds__(64,1). LDS 32KB -> 4 blocks/CU = the
// same ~4 waves/CU concurrency R19-21 ran at. No spill expected (<450 regs).
// K loop: 16 tiles BK=64 fp8, 2 x 16KB buffers, depth-1 vmcnt(16), zero
// barriers. Tail: W / W^T fp8 tiles (16KB each) into the freed buffers.
__global__ __launch_bounds__(64, 1) void mega_gemm(
        const unsigned char* __restrict__ Mf, const unsigned char* __restrict__ Pf,
        const unsigned char* __restrict__ Wg,
        float* __restrict__ outs) {
    __shared__ char smem[32768] __attribute__((aligned(16)));

    int lane = threadIdx.x;
    int lr = lane & 15, lg = lane >> 4;

    // ---- tile decode ----
    int b = (blockIdx.x & 7) * 260 + (blockIdx.x >> 3);
    int bi, bj, mode;
    const unsigned char *A, *Bm;
    if (b < 1024) {
        int st = b >> 4;                    // supertile 0..63 (8x8 grid)
        int sb = b & 15;                    // 4x4 within supertile
        bi = (st >> 3) * 4 + (sb >> 2);
        bj = (st & 7) * 4 + (sb & 3);
        A = Mf; Bm = Pf; mode = 0;
    } else {
        int s = b - 1024;
        int md = (s >= 528) ? 1 : 0;
        s -= md * 528;
        bi = 0;
        while (s >= 32 - bi) { s -= 32 - bi; ++bi; }
        bj = bi + s;
        A = md ? Pf : Mf; Bm = A;
        mode = 1 + md;
    }
    bool offdiag = (bi != bj);
    size_t rowBase = (size_t)bi * 128;
    size_t colBase = (size_t)bj * 128;
    bool needW2 = (rowBase != colBase);
    float* rowTgt = outs + ((mode == 0) ? 0 : (mode == 1) ? 8192 : 12288);
    float* colTgt = (mode == 0) ? (outs + 4096) : rowTgt;

    // ---- staging addresses: 64B fp8 rows, 4 lanes/row, pre-swizzled chunk --
    int sr = lane >> 2;                        // row 0..15 within 1KB unit
    int scs = (lane & 3) ^ (sr & 3) ^ ((sr >> 2) & 3);   // 16B chunk
    const unsigned char* gA = A + (rowBase + sr) * ND + scs * 16;
    const unsigned char* gB = Bm + (colBase + sr) * ND + scs * 16;

    f32x4 acc[8][8] = {};

    // per tile: A 128x64B (8KB) + B 128x64B (8KB); 16 x 1KB issues per wave
#define STAGE(bufi, t) {                                                    \
        int k0_ = (t) * 64;                                                 \
        char* base_ = smem + (bufi) * 16384;                                \
        _Pragma("unroll")                                                   \
        for (int c = 0; c < 8; ++c) {                                       \
            gload16(gA + (size_t)(c * 16) * ND + k0_, base_ + c * 1024);    \
            gload16(gB + (size_t)(c * 16) * ND + k0_, base_ + 8192 + c * 1024); \
        }                                                                   \
    }
// W-tile staging: 16KB = 128 rows x 128B, 16 x 1KB issues (R17's pattern)
#define STAGEW(dst, rbase, cbase) {                                         \
        _Pragma("unroll")                                                   \
        for (int c = 0; c < 16; ++c) {                                      \
            int sw_ = 8 * c + (lane >> 3);            /* W row 0..127 */    \
            int gch_ = (lane & 7) ^ (sw_ & 7);        /* src pre-swizzle */ \
            gload16(Wg + ((rbase) + sw_) * (size_t)NB + (cbase) + gch_ * 16,\
                    (dst) + c * 1024);                                      \
        }                                                                   \
    }
#define COMPUTE(bufi) {                                                     \
        const unsigned char* sA = (const unsigned char*)(smem + (bufi) * 16384); \
        const unsigned char* sB = sA + 8192;                                \
        int rx = (lr & 3) ^ ((lr >> 2) & 3);                                \
        _Pragma("unroll")                                                   \
        for (int ks = 0; ks < 2; ++ks) {                                    \
            int cp = (((ks * 2) + (lg >> 1)) ^ rx) * 16 + (lg & 1) * 8;     \
            long av[8], bv[8];                                              \
            _Pragma("unroll")                                               \
            for (int n = 0; n < 8; ++n)                                     \
                bv[n] = *(const long*)&sB[(n * 16 + lr) * 64 + cp];         \
            _Pragma("unroll")                                               \
            for (int i = 0; i < 8; ++i)                                     \
                av[i] = *(const long*)&sA[(i * 16 + lr) * 64 + cp];         \
            _Pragma("unroll")                                               \
            for (int i = 0; i < 8; ++i)                                     \
                _Pragma("unroll")                                           \
                for (int n = 0; n < 8; ++n)                                 \
                    acc[i][n] = __builtin_amdgcn_mfma_f32_16x16x32_fp8_fp8( \
                        av[i], bv[n], acc[i][n], 0, 0, 0);                  \
        }                                                                   \
        asm volatile("s_waitcnt lgkmcnt(0)" ::: "memory");                  \
    }

    // barrier-free depth-1 pipeline: buffer t&1 holds tile t. 16 loads/tile.
    STAGE(0, 0);
    for (int t = 0; t < 15; ++t) {
        STAGE((t + 1) & 1, t + 1);
        asm volatile("s_waitcnt vmcnt(16)" ::: "memory");  // tile t ready
        COMPUTE(t & 1);
    }
    // staged through 15 (buf1, 16 outstanding); buf0 (tile 14) is free.
    STAGEW(smem, rowBase, colBase);                        // W1 -> buf0
    asm volatile("s_waitcnt vmcnt(16)" ::: "memory");      // tile 15 landed
    COMPUTE(1);                                            // tile 15
    if (needW2) STAGEW(smem + 16384, colBase, rowBase);    // W2 -> buf1
    asm volatile("s_waitcnt vmcnt(0)" ::: "memory");       // W tiles ready
#undef STAGE
#undef STAGEW
#undef COMPUTE

    // ---- epilogue: W1 = W[i-tile][j-tile], W2 = W[j-tile][i-tile] ----
    const unsigned char* wl1 = (const unsigned char*)smem;
    const unsigned char* wl2 = needW2 ? (const unsigned char*)smem + 16384
                                      : (const unsigned char*)smem;
    float d1 = 0.f;
    float cexp[8] = {0.f, 0.f, 0.f, 0.f, 0.f, 0.f, 0.f, 0.f};

#pragma unroll
    for (int m = 0; m < 8; ++m) {
        float rexp[4] = {0.f, 0.f, 0.f, 0.f};
#pragma unroll
        for (int n = 0; n < 8; ++n) {
            int jl = n * 16 + lr;               // 0..127
#pragma unroll
            for (int r = 0; r < 4; ++r) {
                int rl = m * 16 + lg * 4 + r;   // 0..127
                float sim = acc[m][n][r] * INV_T;
                float e = __expf(sim - INV_T);
                rexp[r] += e;
                cexp[n] += e;
                float w1v = fp82f(wl1[rl * 128 +
                    (((jl >> 4) ^ (rl & 7)) << 4) + (jl & 15)]);
                float w2v = fp82f(wl2[jl * 128 +
                    (((rl >> 4) ^ (jl & 7)) << 4) + (rl & 15)]);
                d1 += (w1v + w2v) * sim;
            }
        }
#pragma unroll
        for (int r = 0; r < 4; ++r) {
            float v = rexp[r];
            v += __shfl_xor(v, 1); v += __shfl_xor(v, 2);
            v += __shfl_xor(v, 4); v += __shfl_xor(v, 8);
            if (lr == 0)
                atomicAdd(&rowTgt[rowBase + m * 16 + lg * 4 + r], v);
        }
    }

    // col-exp sums: cross always; symmetric only for offdiag tiles
    if (mode == 0 || offdiag) {
#pragma unroll
        for (int n = 0; n < 8; ++n) {
            float v = cexp[n];
            v += __shfl_xor(v, 16); v += __shfl_xor(v, 32);
            if (lg == 0)
                atomicAdd(&colTgt[colBase + n * 16 + lr], v);
        }
    }

    // weighted dot: (W + W^T) covers (i,j)+(j,i). diag sym tile counts half.
    float dtot = (mode != 0 && !offdiag) ? 0.5f * d1 : d1;
    for (int off = 32; off; off >>= 1) dtot += __shfl_xor(dtot, off);
    if (lane == 0) {
        float* dots = outs + 16384;
        if (mode == 0) atomicAdd(&dots[0], dtot);
        else           atomicAdd(&dots[1 + mode], dtot);
    }
}

// ---------------- kernel 4: finalize --------------------------------------
__global__ __launch_bounds__(256) void finalize_kernel(
        const float* __restrict__ outs, const float* __restrict__ flag,
        float* __restrict__ out) {
    const float* rowsum1 = outs;
    const float* colsum1 = outs + 4096;
    const float* rowsum3 = outs + 8192;
    const float* rowsum4 = outs + 12288;
    const float* dots = outs + 16384;
    int tid = threadIdx.x;
    float l = 0.f;
    for (int i = tid; i < NB; i += 256) {
        if (flag[i] != 0.f) {
            l += 4.f * INV_T + logf(rowsum1[i]) + logf(colsum1[i]) +
                 logf(rowsum3[i]) + logf(rowsum4[i]);
        }
    }
    for (int off = 32; off; off >>= 1) l += __shfl_down(l, off);
    __shared__ float red[4];
    int lane = tid & 63, w = tid >> 6;
    if (lane == 0) red[w] = l;
    __syncthreads();
    if (tid == 0) {
        float L = red[0] + red[1] + red[2] + red[3];
        float dt = dots[0] + dots[1] + dots[2] + dots[3];
        out[0] = (L - dt) / (4.0f * (float)NB);
    }
}

extern "C" void kernel_launch(void* const* d_in, const int* in_sizes, int n_in,
                              void* d_out, int out_size, void* d_ws, size_t ws_size,
                              hipStream_t stream) {
    const float* M = (const float*)d_in[0];
    const float* P = (const float*)d_in[1];
    const int* labels = (const int*)d_in[2];
    const int* sm = (const int*)d_in[3];
    const int* sp = (const int*)d_in[4];
    const float* cs = (const float*)d_in[5];
    float* out = (float*)d_out;

    char* ws = (char*)d_ws;
    unsigned char* Mf = (unsigned char*)ws;                                // 4 MB
    unsigned char* Pf = (unsigned char*)(ws + (size_t)4 * 1024 * 1024);    // 4 MB
    unsigned char* W = (unsigned char*)(ws + (size_t)16 * 1024 * 1024);    // 16 MB
    char* p = ws + (size_t)48 * 1024 * 1024;
    int* code = (int*)p;    p += 16384;
    float* flag = (float*)p; p += 16384;
    float* outs = (float*)p;   // rowsum1|colsum1|rowsum3|rowsum4|dots

    hipMemsetAsync(outs, 0, 4 * 16384 + 256, stream);

    norm_kernel<<<2 * NB, 256, 0, stream>>>(M, P, Mf, Pf);
    key_kernel<<<NB / 256, 256, 0, stream>>>(labels, sm, sp, code);
    rowsumw_kernel<<<NB, 256, 0, stream>>>(cs, code, W, flag);

    mega_gemm<<<2080, 64, 0, stream>>>(Mf, Pf, W, outs);

    finalize_kernel<<<1, 256, 0, stream>>>(outs, flag, out);
}

// Round 24
// 193.484 us; speedup vs baseline: 2.1723x; 2.1723x over previous
//
#include <hip/hip_runtime.h>
#include <hip/hip_bf16.h>
#include <hip/hip_fp8.h>
#include <math.h>

typedef __attribute__((ext_vector_type(4))) float f32x4;

#define NB 4096
#define ND 1024
#define INV_T 14.2857142857142857f   // 1/0.07

__device__ inline float fp82f(unsigned char b) {
    __hip_fp8_e4m3 h; h.__x = b;
    return (float)h;
}
__device__ inline void gload16(const void* g, void* l) {
    __builtin_amdgcn_global_load_lds(
        (const __attribute__((address_space(1))) void*)g,
        (__attribute__((address_space(3))) void*)l, 16, 0, 0);
}

// ---------------- kernel 0: L2-normalize rows, cast to fp8 e4m3 -------------
__global__ __launch_bounds__(256) void norm_kernel(
        const float* __restrict__ M, const float* __restrict__ P,
        unsigned char* __restrict__ Mf, unsigned char* __restrict__ Pf) {
    int row = blockIdx.x & (NB - 1);
    const float* src = (blockIdx.x < NB) ? M : P;
    unsigned char* dst = (blockIdx.x < NB) ? Mf : Pf;
    int tid = threadIdx.x;
    float4 v = ((const float4*)(src + (size_t)row * ND))[tid];
    float ss = v.x * v.x + v.y * v.y + v.z * v.z + v.w * v.w;
    for (int off = 32; off; off >>= 1) ss += __shfl_down(ss, off);
    __shared__ float red[4];
    int lane = tid & 63, w = tid >> 6;
    if (lane == 0) red[w] = ss;
    __syncthreads();
    float rn = rsqrtf(red[0] + red[1] + red[2] + red[3]);
    int p = __builtin_amdgcn_cvt_pk_fp8_f32(v.x * rn, v.y * rn, 0, false);
    p = __builtin_amdgcn_cvt_pk_fp8_f32(v.z * rn, v.w * rn, p, true);
    ((int*)dst)[row * 256 + tid] = p;
}

// ---------------- kernel 1: per-row mask codes ------------------------------
__global__ __launch_bounds__(256) void key_kernel(
        const int* __restrict__ labels, const int* __restrict__ sm,
        const int* __restrict__ sp, int* __restrict__ code) {
    int i = blockIdx.x * 256 + threadIdx.x;
    if (i < NB) {
        int l = labels[i];
        code[i] = (l == 0) ? 0x40000000 : (1 + l + (sm[i] << 8) + (sp[i] << 16));
    }
}

// ------- kernel 2: fused row-sum + normalized masked weight matrix (fp8) ----
__global__ __launch_bounds__(256) void rowsumw_kernel(
        const float* __restrict__ cs, const int* __restrict__ code,
        unsigned char* __restrict__ W, float* __restrict__ flag) {
    int i = blockIdx.x;
    int ci = code[i];
    int tid = threadIdx.x;
    const float4* row = (const float4*)(cs + (size_t)i * NB);
    const int4* c4 = (const int4*)code;
    float4 v[4];
    int4 cj[4];
    float s = 0.f;
#pragma unroll
    for (int k = 0; k < 4; ++k) {
        int t = tid + k * 256;
        v[k] = row[t];
        cj[k] = c4[t];
        int j = t * 4;
        if (cj[k].x == ci && j + 0 != i) s += v[k].x;
        if (cj[k].y == ci && j + 1 != i) s += v[k].y;
        if (cj[k].z == ci && j + 2 != i) s += v[k].z;
        if (cj[k].w == ci && j + 3 != i) s += v[k].w;
    }
    for (int off = 1; off < 64; off <<= 1) s += __shfl_xor(s, off);
    __shared__ float red[4];
    int lane = tid & 63, w = tid >> 6;
    if (lane == 0) red[w] = s;
    __syncthreads();
    float tot = red[0] + red[1] + red[2] + red[3];
    float inv = (tot > 0.f) ? 1.f / tot : 0.f;
#pragma unroll
    for (int k = 0; k < 4; ++k) {
        int t = tid + k * 256;
        int j = t * 4;
        float f0 = (cj[k].x == ci && j + 0 != i) ? v[k].x * inv : 0.f;
        float f1 = (cj[k].y == ci && j + 1 != i) ? v[k].y * inv : 0.f;
        float f2 = (cj[k].z == ci && j + 2 != i) ? v[k].z * inv : 0.f;
        float f3 = (cj[k].w == ci && j + 3 != i) ? v[k].w * inv : 0.f;
        int p = __builtin_amdgcn_cvt_pk_fp8_f32(f0, f1, 0, false);
        p = __builtin_amdgcn_cvt_pk_fp8_f32(f2, f3, p, true);
        ((int*)W)[((size_t)i * NB + j) >> 2] = p;
    }
    if (tid == 0) flag[i] = (tot > 0.f) ? 1.f : 0.f;
}

// ---------------- kernel 3: 1-WAVE barrier-free fp8 128x64-tile GEMM --------
// 4160 blocks (XCD-chunked, 4160 = 8*520), 64 threads = ONE wave.
//   b < 2048: cross S1 = Mf Pf^T, 32(row128) x 64(col64) grid, supertiled.
//   b >= 2048: symmetric (Mf then Pf), tiles (r,c) with c >= 2r (1056 each).
//     c >= 2r+2: fully offdiag -> cexp on, d full.
//     c in {2r,2r+1}: diagonal overlap -> cexp OFF (transposed cells are
//     covered by another included tile's rexp), d x 0.5 (each unordered
//     pair appears in exactly two included tiles).
// acc[8][4] = 128 AGPR + ~110 arch ~= 240 <= the 256 arch cap -> NO spill
// (R23's acc[8][8]=256 AGPR could never fit). Barrier-free self-paced
// staging (92 cy/KB, R19-21) at 85 FLOP/B: staged bytes 1.06GB -> 0.80GB.
// K loop: 16 tiles BK=64 fp8, 2 x 12KB buffers, depth-1 vmcnt(12), zero
// barriers. Tail: W1 (128x64) + W2 (64x128) fp8 tiles into a 16KB W region.
__global__ __launch_bounds__(64) void mega_gemm(
        const unsigned char* __restrict__ Mf, const unsigned char* __restrict__ Pf,
        const unsigned char* __restrict__ Wg,
        float* __restrict__ outs) {
    __shared__ char smem[40960] __attribute__((aligned(16)));

    int lane = threadIdx.x;
    int lr = lane & 15, lg = lane >> 4;

    // ---- tile decode ----
    int b = (blockIdx.x & 7) * 520 + (blockIdx.x >> 3);
    int bi, bj, mode;         // bi: 128-row block 0..31, bj: 64-col block 0..63
    const unsigned char *A, *Bm;
    if (b < 2048) {
        int st = b >> 3;                    // supertile 0..255 (16x16)
        int sb = b & 7;                     // 2x4 within supertile
        bi = (st >> 4) * 2 + (sb >> 2);
        bj = (st & 15) * 4 + (sb & 3);
        A = Mf; Bm = Pf; mode = 0;
    } else {
        int s = b - 2048;
        int md = (s >= 1056) ? 1 : 0;
        s -= md * 1056;
        bi = 0;
        while (s >= 64 - 2 * bi) { s -= 64 - 2 * bi; ++bi; }
        bj = 2 * bi + s;
        A = md ? Pf : Mf; Bm = A;
        mode = 1 + md;
    }
    bool fullOff = (mode == 0) || (bj >= 2 * bi + 2);
    size_t rowBase = (size_t)bi * 128;
    size_t colBase = (size_t)bj * 64;
    float* rowTgt = outs + ((mode == 0) ? 0 : (mode == 1) ? 8192 : 12288);
    float* colTgt = (mode == 0) ? (outs + 4096) : rowTgt;

    // ---- staging addresses: 64B fp8 rows, 4 lanes/row, pre-swizzled chunk --
    int sr = lane >> 2;                        // row 0..15 within 1KB unit
    int scs = (lane & 3) ^ (sr & 3) ^ ((sr >> 2) & 3);   // 16B chunk
    const unsigned char* gA = A + (rowBase + sr) * ND + scs * 16;
    const unsigned char* gB = Bm + (colBase + sr) * ND + scs * 16;

    f32x4 acc[8][4] = {};

    // per tile: A 128x64B (8KB, 8 units) + B 64x64B (4KB, 4 units) = 12KB
#define STAGE(bufi, t) {                                                    \
        int k0_ = (t) * 64;                                                 \
        char* base_ = smem + (bufi) * 12288;                                \
        _Pragma("unroll")                                                   \
        for (int c = 0; c < 8; ++c)                                         \
            gload16(gA + (size_t)(c * 16) * ND + k0_, base_ + c * 1024);    \
        _Pragma("unroll")                                                   \
        for (int c = 0; c < 4; ++c)                                         \
            gload16(gB + (size_t)(c * 16) * ND + k0_, base_ + 8192 + c * 1024); \
    }
// W1: 128 rows x 64 cols (64B rows, A-style swizzle), 8 x 1KB issues
#define STAGEW1(dst) {                                                      \
        _Pragma("unroll")                                                   \
        for (int c = 0; c < 8; ++c)                                         \
            gload16(Wg + (rowBase + c * 16 + sr) * (size_t)NB + colBase + scs * 16, \
                    (dst) + c * 1024);                                      \
    }
// W2: 64 rows x 128 cols (128B rows, R17-style swizzle), 8 x 1KB issues
#define STAGEW2(dst) {                                                      \
        _Pragma("unroll")                                                   \
        for (int c = 0; c < 8; ++c) {                                       \
            int sw_ = 8 * c + (lane >> 3);            /* W row 0..63 */     \
            int gch_ = (lane & 7) ^ (sw_ & 7);                              \
            gload16(Wg + (colBase + sw_) * (size_t)NB + rowBase + gch_ * 16,\
                    (dst) + c * 1024);                                      \
        }                                                                   \
    }
#define COMPUTE(bufi) {                                                     \
        const unsigned char* sA = (const unsigned char*)(smem + (bufi) * 12288); \
        const unsigned char* sB = sA + 8192;                                \
        int rx = (lr & 3) ^ ((lr >> 2) & 3);                                \
        _Pragma("unroll")                                                   \
        for (int ks = 0; ks < 2; ++ks) {                                    \
            int cp = (((ks * 2) + (lg >> 1)) ^ rx) * 16 + (lg & 1) * 8;     \
            long av[8], bv[4];                                              \
            _Pragma("unroll")                                               \
            for (int n = 0; n < 4; ++n)                                     \
                bv[n] = *(const long*)&sB[(n * 16 + lr) * 64 + cp];         \
            _Pragma("unroll")                                               \
            for (int i = 0; i < 8; ++i)                                     \
                av[i] = *(const long*)&sA[(i * 16 + lr) * 64 + cp];         \
            _Pragma("unroll")                                               \
            for (int i = 0; i < 8; ++i)                                     \
                _Pragma("unroll")                                           \
                for (int n = 0; n < 4; ++n)                                 \
                    acc[i][n] = __builtin_amdgcn_mfma_f32_16x16x32_fp8_fp8( \
                        av[i], bv[n], acc[i][n], 0, 0, 0);                  \
        }                                                                   \
        asm volatile("s_waitcnt lgkmcnt(0)" ::: "memory");                  \
    }

    // barrier-free depth-1 pipeline: buffer t&1 holds tile t. 12 loads/tile.
    STAGE(0, 0);
    for (int t = 0; t < 15; ++t) {
        STAGE((t + 1) & 1, t + 1);
        asm volatile("s_waitcnt vmcnt(12)" ::: "memory");  // tile t ready
        COMPUTE(t & 1);
    }
    // staged through 15 (buf1, 12 outstanding); W region at [24K, 40K).
    STAGEW1(smem + 24576);                                 // +8 -> 20
    STAGEW2(smem + 32768);                                 // +8 -> 28
    asm volatile("s_waitcnt vmcnt(16)" ::: "memory");      // tile 15 landed
    COMPUTE(1);                                            // tile 15
    asm volatile("s_waitcnt vmcnt(0)" ::: "memory");       // W tiles ready
#undef STAGE
#undef STAGEW1
#undef STAGEW2
#undef COMPUTE

    // ---- epilogue: W1 = W[rows, cols], W2 = W[cols, rows] ----
    const unsigned char* wl1 = (const unsigned char*)smem + 24576;
    const unsigned char* wl2 = (const unsigned char*)smem + 32768;
    float d1 = 0.f;
    float cexp[4] = {0.f, 0.f, 0.f, 0.f};

#pragma unroll
    for (int m = 0; m < 8; ++m) {
        float rexp[4] = {0.f, 0.f, 0.f, 0.f};
#pragma unroll
        for (int n = 0; n < 4; ++n) {
            int jl = n * 16 + lr;               // 0..63
#pragma unroll
            for (int r = 0; r < 4; ++r) {
                int rl = m * 16 + lg * 4 + r;   // 0..127
                float sim = acc[m][n][r] * INV_T;
                float e = __expf(sim - INV_T);
                rexp[r] += e;
                cexp[n] += e;
                float w1v = fp82f(wl1[rl * 64 +
                    (((jl >> 4) ^ (rl & 3) ^ ((rl >> 2) & 3)) << 4) + (jl & 15)]);
                float w2v = fp82f(wl2[jl * 128 +
                    (((rl >> 4) ^ (jl & 7)) << 4) + (rl & 15)]);
                d1 += (w1v + w2v) * sim;
            }
        }
#pragma unroll
        for (int r = 0; r < 4; ++r) {
            float v = rexp[r];
            v += __shfl_xor(v, 1); v += __shfl_xor(v, 2);
            v += __shfl_xor(v, 4); v += __shfl_xor(v, 8);
            if (lr == 0)
                atomicAdd(&rowTgt[rowBase + m * 16 + lg * 4 + r], v);
        }
    }

    // col-exp sums: cross always; symmetric only for fully-offdiag tiles
    if (fullOff) {
#pragma unroll
        for (int n = 0; n < 4; ++n) {
            float v = cexp[n];
            v += __shfl_xor(v, 16); v += __shfl_xor(v, 32);
            if (lg == 0)
                atomicAdd(&colTgt[colBase + n * 16 + lr], v);
        }
    }

    // weighted dot: (W+W^T) covers both orders; overlap tiles count half.
    float dtot = (mode != 0 && !fullOff) ? 0.5f * d1 : d1;
    for (int off = 32; off; off >>= 1) dtot += __shfl_xor(dtot, off);
    if (lane == 0) {
        float* dots = outs + 16384;
        if (mode == 0) atomicAdd(&dots[0], dtot);
        else           atomicAdd(&dots[1 + mode], dtot);
    }
}

// ---------------- kernel 4: finalize --------------------------------------
__global__ __launch_bounds__(256) void finalize_kernel(
        const float* __restrict__ outs, const float* __restrict__ flag,
        float* __restrict__ out) {
    const float* rowsum1 = outs;
    const float* colsum1 = outs + 4096;
    const float* rowsum3 = outs + 8192;
    const float* rowsum4 = outs + 12288;
    const float* dots = outs + 16384;
    int tid = threadIdx.x;
    float l = 0.f;
    for (int i = tid; i < NB; i += 256) {
        if (flag[i] != 0.f) {
            l += 4.f * INV_T + logf(rowsum1[i]) + logf(colsum1[i]) +
                 logf(rowsum3[i]) + logf(rowsum4[i]);
        }
    }
    for (int off = 32; off; off >>= 1) l += __shfl_down(l, off);
    __shared__ float red[4];
    int lane = tid & 63, w = tid >> 6;
    if (lane == 0) red[w] = l;
    __syncthreads();
    if (tid == 0) {
        float L = red[0] + red[1] + red[2] + red[3];
        float dt = dots[0] + dots[1] + dots[2] + dots[3];
        out[0] = (L - dt) / (4.0f * (float)NB);
    }
}

extern "C" void kernel_launch(void* const* d_in, const int* in_sizes, int n_in,
                              void* d_out, int out_size, void* d_ws, size_t ws_size,
                              hipStream_t stream) {
    const float* M = (const float*)d_in[0];
    const float* P = (const float*)d_in[1];
    const int* labels = (const int*)d_in[2];
    const int* sm = (const int*)d_in[3];
    const int* sp = (const int*)d_in[4];
    const float* cs = (const float*)d_in[5];
    float* out = (float*)d_out;

    char* ws = (char*)d_ws;
    unsigned char* Mf = (unsigned char*)ws;                                // 4 MB
    unsigned char* Pf = (unsigned char*)(ws + (size_t)4 * 1024 * 1024);    // 4 MB
    unsigned char* W = (unsigned char*)(ws + (size_t)16 * 1024 * 1024);    // 16 MB
    char* p = ws + (size_t)48 * 1024 * 1024;
    int* code = (int*)p;    p += 16384;
    float* flag = (float*)p; p += 16384;
    float* outs = (float*)p;   // rowsum1|colsum1|rowsum3|rowsum4|dots

    hipMemsetAsync(outs, 0, 4 * 16384 + 256, stream);

    norm_kernel<<<2 * NB, 256, 0, stream>>>(M, P, Mf, Pf);
    key_kernel<<<NB / 256, 256, 0, stream>>>(labels, sm, sp, code);
    rowsumw_kernel<<<NB, 256, 0, stream>>>(cs, code, W, flag);

    mega_gemm<<<4160, 64, 0, stream>>>(Mf, Pf, W, outs);

    finalize_kernel<<<1, 256, 0, stream>>>(outs, flag, out);
}

// Round 25
// 191.435 us; speedup vs baseline: 2.1956x; 1.0107x over previous
//
#include <hip/hip_runtime.h>
#include <hip/hip_bf16.h>
#include <hip/hip_fp8.h>
#include <math.h>

typedef __attribute__((ext_vector_type(4))) float f32x4;

#define NB 4096
#define ND 1024
#define INV_T 14.2857142857142857f   // 1/0.07

__device__ inline float fp82f(unsigned char b) {
    __hip_fp8_e4m3 h; h.__x = b;
    return (float)h;
}
__device__ inline void gload16(const void* g, void* l) {
    __builtin_amdgcn_global_load_lds(
        (const __attribute__((address_space(1))) void*)g,
        (__attribute__((address_space(3))) void*)l, 16, 0, 0);
}

// ---------------- kernel 0: L2-normalize rows, cast to fp8 e4m3 -------------
__global__ __launch_bounds__(256) void norm_kernel(
        const float* __restrict__ M, const float* __restrict__ P,
        unsigned char* __restrict__ Mf, unsigned char* __restrict__ Pf) {
    int row = blockIdx.x & (NB - 1);
    const float* src = (blockIdx.x < NB) ? M : P;
    unsigned char* dst = (blockIdx.x < NB) ? Mf : Pf;
    int tid = threadIdx.x;
    float4 v = ((const float4*)(src + (size_t)row * ND))[tid];
    float ss = v.x * v.x + v.y * v.y + v.z * v.z + v.w * v.w;
    for (int off = 32; off; off >>= 1) ss += __shfl_down(ss, off);
    __shared__ float red[4];
    int lane = tid & 63, w = tid >> 6;
    if (lane == 0) red[w] = ss;
    __syncthreads();
    float rn = rsqrtf(red[0] + red[1] + red[2] + red[3]);
    int p = __builtin_amdgcn_cvt_pk_fp8_f32(v.x * rn, v.y * rn, 0, false);
    p = __builtin_amdgcn_cvt_pk_fp8_f32(v.z * rn, v.w * rn, p, true);
    ((int*)dst)[row * 256 + tid] = p;
}

// ---------------- kernel 1: per-row mask codes ------------------------------
__global__ __launch_bounds__(256) void key_kernel(
        const int* __restrict__ labels, const int* __restrict__ sm,
        const int* __restrict__ sp, int* __restrict__ code) {
    int i = blockIdx.x * 256 + threadIdx.x;
    if (i < NB) {
        int l = labels[i];
        code[i] = (l == 0) ? 0x40000000 : (1 + l + (sm[i] << 8) + (sp[i] << 16));
    }
}

// ------- kernel 2: fused row-sum + normalized masked weight matrix (fp8) ----
__global__ __launch_bounds__(256) void rowsumw_kernel(
        const float* __restrict__ cs, const int* __restrict__ code,
        unsigned char* __restrict__ W, float* __restrict__ flag) {
    int i = blockIdx.x;
    int ci = code[i];
    int tid = threadIdx.x;
    const float4* row = (const float4*)(cs + (size_t)i * NB);
    const int4* c4 = (const int4*)code;
    float4 v[4];
    int4 cj[4];
    float s = 0.f;
#pragma unroll
    for (int k = 0; k < 4; ++k) {
        int t = tid + k * 256;
        v[k] = row[t];
        cj[k] = c4[t];
        int j = t * 4;
        if (cj[k].x == ci && j + 0 != i) s += v[k].x;
        if (cj[k].y == ci && j + 1 != i) s += v[k].y;
        if (cj[k].z == ci && j + 2 != i) s += v[k].z;
        if (cj[k].w == ci && j + 3 != i) s += v[k].w;
    }
    for (int off = 1; off < 64; off <<= 1) s += __shfl_xor(s, off);
    __shared__ float red[4];
    int lane = tid & 63, w = tid >> 6;
    if (lane == 0) red[w] = s;
    __syncthreads();
    float tot = red[0] + red[1] + red[2] + red[3];
    float inv = (tot > 0.f) ? 1.f / tot : 0.f;
#pragma unroll
    for (int k = 0; k < 4; ++k) {
        int t = tid + k * 256;
        int j = t * 4;
        float f0 = (cj[k].x == ci && j + 0 != i) ? v[k].x * inv : 0.f;
        float f1 = (cj[k].y == ci && j + 1 != i) ? v[k].y * inv : 0.f;
        float f2 = (cj[k].z == ci && j + 2 != i) ? v[k].z * inv : 0.f;
        float f3 = (cj[k].w == ci && j + 3 != i) ? v[k].w * inv : 0.f;
        int p = __builtin_amdgcn_cvt_pk_fp8_f32(f0, f1, 0, false);
        p = __builtin_amdgcn_cvt_pk_fp8_f32(f2, f3, p, true);
        ((int*)W)[((size_t)i * NB + j) >> 2] = p;
    }
    if (tid == 0) flag[i] = (tot > 0.f) ? 1.f : 0.f;
}

// ---------------- kernel 3: 4x(1-wave) barrier-free fp8 64x64-tile GEMM -----
// R21 configuration (session-best total 183.5 us, absmax 0.0), reverted
// verbatim after R22/R23/R24 falsified the remaining structural hypotheses:
//   - R22 (fp8 256^2 lockstep): spill (128-AGPR acc caps arch at 128).
//   - R23 (1-wave acc[8][8]): 256-AGPR acc can never fit the 256-arch file.
//   - R24 (1-wave acc[8][4], no spill): mega invariant at ~164 us -> the
//     limiter is an effective ~3-waves/CU concurrency cap on the self-paced
//     staging stream, not bytes, depth, dispatch, or registers.
// 2064 workgroups (XCD-chunked, 2064 = 8*258) x 256 threads = 4 INDEPENDENT
// waves; wave w owns logical tile b*4+w and a private 16KB LDS slice; zero
// __syncthreads. Depth-1 counted-vmcnt pipeline; dual-W epilogue (no symw).
__global__ __launch_bounds__(256) void mega_gemm(
        const unsigned char* __restrict__ Mf, const unsigned char* __restrict__ Pf,
        const unsigned char* __restrict__ Wg,
        float* __restrict__ outs) {
    __shared__ char smem[65536] __attribute__((aligned(16)));

    int tid = threadIdx.x;
    int lane = tid & 63;
    char* bs = smem + (tid >> 6) * 16384;      // this wave's private slice
    int lr = lane & 15, lg = lane >> 4;

    // ---- tile decode ----
    int b = ((blockIdx.x & 7) * 258 + (blockIdx.x >> 3)) * 4 + (tid >> 6);
    int bi, bj, mode;
    const unsigned char *A, *Bm;
    if (b < 4096) {
        int st = b >> 4;                    // supertile 0..255 (16x16 grid)
        int sb = b & 15;                    // 4x4 within supertile
        bi = (st >> 4) * 4 + (sb >> 2);
        bj = (st & 15) * 4 + (sb & 3);
        A = Mf; Bm = Pf; mode = 0;
    } else {
        int s = b - 4096;
        int md = (s >= 2080) ? 1 : 0;
        s -= md * 2080;
        bi = 0;
        while (s >= 64 - bi) { s -= 64 - bi; ++bi; }
        bj = bi + s;
        A = md ? Pf : Mf; Bm = A;
        mode = 1 + md;
    }
    bool offdiag = (bi != bj);
    size_t rowBase = (size_t)bi * 64;
    size_t colBase = (size_t)bj * 64;
    bool needW2 = (rowBase != colBase);
    float* rowTgt = outs + ((mode == 0) ? 0 : (mode == 1) ? 8192 : 12288);
    float* colTgt = (mode == 0) ? (outs + 4096) : rowTgt;

    // ---- staging addresses: 64B fp8 rows, 4 lanes/row, pre-swizzled chunk --
    int sr = lane >> 2;                        // row 0..15 within 1KB unit
    int scs = (lane & 3) ^ (sr & 3) ^ ((sr >> 2) & 3);   // 16B chunk
    const unsigned char* gA = A + (rowBase + sr) * ND + scs * 16;
    const unsigned char* gB = Bm + (colBase + sr) * ND + scs * 16;

    f32x4 acc[4][4] = {};

    // per tile: A 64x64B (4KB) + B 64x64B (4KB); 8 x 1KB issues per wave
#define STAGE(bufi, t) {                                                    \
        int k0_ = (t) * 64;                                                 \
        char* base_ = bs + (bufi) * 8192;                                   \
        _Pragma("unroll")                                                   \
        for (int c = 0; c < 4; ++c) {                                       \
            gload16(gA + (size_t)(c * 16) * ND + k0_, base_ + c * 1024);    \
            gload16(gB + (size_t)(c * 16) * ND + k0_, base_ + 4096 + c * 1024); \
        }                                                                   \
    }
// W-tile staging: 4KB = 64 rows x 64B, 4 x 1KB issues, same swizzle as A
#define STAGEW(dst, rbase, cbase) {                                         \
        _Pragma("unroll")                                                   \
        for (int c = 0; c < 4; ++c) {                                       \
            gload16(Wg + ((rbase) + c * 16 + sr) * (size_t)NB + (cbase) + scs * 16, \
                    (dst) + c * 1024);                                      \
        }                                                                   \
    }
#define COMPUTE(bufi) {                                                     \
        const unsigned char* sA = (const unsigned char*)(bs + (bufi) * 8192); \
        const unsigned char* sB = sA + 4096;                                \
        int rx = (lr & 3) ^ ((lr >> 2) & 3);                                \
        _Pragma("unroll")                                                   \
        for (int ks = 0; ks < 2; ++ks) {                                    \
            int cp = (((ks * 2) + (lg >> 1)) ^ rx) * 16 + (lg & 1) * 8;     \
            long av[4], bv[4];                                              \
            _Pragma("unroll")                                               \
            for (int n = 0; n < 4; ++n)                                     \
                bv[n] = *(const long*)&sB[(n * 16 + lr) * 64 + cp];         \
            _Pragma("unroll")                                               \
            for (int i = 0; i < 4; ++i)                                     \
                av[i] = *(const long*)&sA[(i * 16 + lr) * 64 + cp];         \
            _Pragma("unroll")                                               \
            for (int i = 0; i < 4; ++i)                                     \
                _Pragma("unroll")                                           \
                for (int n = 0; n < 4; ++n)                                 \
                    acc[i][n] = __builtin_amdgcn_mfma_f32_16x16x32_fp8_fp8( \
                        av[i], bv[n], acc[i][n], 0, 0, 0);                  \
        }                                                                   \
        asm volatile("s_waitcnt lgkmcnt(0)" ::: "memory");                  \
    }

    // barrier-free depth-1 pipeline: buffer t&1 holds tile t. 8 loads/tile.
    STAGE(0, 0);
    for (int t = 0; t < 15; ++t) {
        STAGE((t + 1) & 1, t + 1);
        asm volatile("s_waitcnt vmcnt(8)" ::: "memory");   // tile t ready
        COMPUTE(t & 1);
    }
    // staged through 15, computed through 14; buf0 (tile 14) is free.
    STAGEW(bs, rowBase, colBase);                          // W1 -> [0,4K)
    if (needW2) {
        STAGEW(bs + 4096, colBase, rowBase);               // W2 -> [4K,8K)
        asm volatile("s_waitcnt vmcnt(8)" ::: "memory");   // tile 15 ready
    } else {
        asm volatile("s_waitcnt vmcnt(4)" ::: "memory");   // tile 15 ready
    }
    COMPUTE(1);                                            // tile 15
    asm volatile("s_waitcnt vmcnt(0)" ::: "memory");       // W tiles ready
#undef STAGE
#undef STAGEW
#undef COMPUTE

    // ---- epilogue: W1 = W[i-tile][j-tile], W2 = W[j-tile][i-tile] ----
    const unsigned char* wl1 = (const unsigned char*)bs;
    const unsigned char* wl2 = needW2 ? (const unsigned char*)bs + 4096
                                      : (const unsigned char*)bs;
    float d1 = 0.f;
    float cexp[4] = {0.f, 0.f, 0.f, 0.f};

#pragma unroll
    for (int m = 0; m < 4; ++m) {
        float rexp[4] = {0.f, 0.f, 0.f, 0.f};
#pragma unroll
        for (int n = 0; n < 4; ++n) {
            int jl = n * 16 + lr;               // 0..63
#pragma unroll
            for (int r = 0; r < 4; ++r) {
                int rl = m * 16 + lg * 4 + r;   // 0..63
                float sim = acc[m][n][r] * INV_T;
                float e = __expf(sim - INV_T);
                rexp[r] += e;
                cexp[n] += e;
                float w1v = fp82f(wl1[rl * 64 +
                    (((jl >> 4) ^ (rl & 3) ^ ((rl >> 2) & 3)) << 4) + (jl & 15)]);
                float w2v = fp82f(wl2[jl * 64 +
                    (((rl >> 4) ^ (jl & 3) ^ ((jl >> 2) & 3)) << 4) + (rl & 15)]);
                d1 += (w1v + w2v) * sim;
            }
        }
#pragma unroll
        for (int r = 0; r < 4; ++r) {
            float v = rexp[r];
            v += __shfl_xor(v, 1); v += __shfl_xor(v, 2);
            v += __shfl_xor(v, 4); v += __shfl_xor(v, 8);
            if (lr == 0)
                atomicAdd(&rowTgt[rowBase + m * 16 + lg * 4 + r], v);
        }
    }

    // col-exp sums: cross always; symmetric only for offdiag tiles
    if (mode == 0 || offdiag) {
#pragma unroll
        for (int n = 0; n < 4; ++n) {
            float v = cexp[n];
            v += __shfl_xor(v, 16); v += __shfl_xor(v, 32);
            if (lg == 0)
                atomicAdd(&colTgt[colBase + n * 16 + lr], v);
        }
    }

    // weighted dot: (W + W^T) covers (i,j)+(j,i). diag sym tile counts half.
    float dtot = (mode != 0 && !offdiag) ? 0.5f * d1 : d1;
    for (int off = 32; off; off >>= 1) dtot += __shfl_xor(dtot, off);
    if (lane == 0) {
        float* dots = outs + 16384;
        if (mode == 0) atomicAdd(&dots[0], dtot);
        else           atomicAdd(&dots[1 + mode], dtot);
    }
}

// ---------------- kernel 4: finalize --------------------------------------
__global__ __launch_bounds__(256) void finalize_kernel(
        const float* __restrict__ outs, const float* __restrict__ flag,
        float* __restrict__ out) {
    const float* rowsum1 = outs;
    const float* colsum1 = outs + 4096;
    const float* rowsum3 = outs + 8192;
    const float* rowsum4 = outs + 12288;
    const float* dots = outs + 16384;
    int tid = threadIdx.x;
    float l = 0.f;
    for (int i = tid; i < NB; i += 256) {
        if (flag[i] != 0.f) {
            l += 4.f * INV_T + logf(rowsum1[i]) + logf(colsum1[i]) +
                 logf(rowsum3[i]) + logf(rowsum4[i]);
        }
    }
    for (int off = 32; off; off >>= 1) l += __shfl_down(l, off);
    __shared__ float red[4];
    int lane = tid & 63, w = tid >> 6;
    if (lane == 0) red[w] = l;
    __syncthreads();
    if (tid == 0) {
        float L = red[0] + red[1] + red[2] + red[3];
        float dt = dots[0] + dots[1] + dots[2] + dots[3];
        out[0] = (L - dt) / (4.0f * (float)NB);
    }
}

extern "C" void kernel_launch(void* const* d_in, const int* in_sizes, int n_in,
                              void* d_out, int out_size, void* d_ws, size_t ws_size,
                              hipStream_t stream) {
    const float* M = (const float*)d_in[0];
    const float* P = (const float*)d_in[1];
    const int* labels = (const int*)d_in[2];
    const int* sm = (const int*)d_in[3];
    const int* sp = (const int*)d_in[4];
    const float* cs = (const float*)d_in[5];
    float* out = (float*)d_out;

    char* ws = (char*)d_ws;
    unsigned char* Mf = (unsigned char*)ws;                                // 4 MB
    unsigned char* Pf = (unsigned char*)(ws + (size_t)4 * 1024 * 1024);    // 4 MB
    unsigned char* W = (unsigned char*)(ws + (size_t)16 * 1024 * 1024);    // 16 MB
    char* p = ws + (size_t)48 * 1024 * 1024;
    int* code = (int*)p;    p += 16384;
    float* flag = (float*)p; p += 16384;
    float* outs = (float*)p;   // rowsum1|colsum1|rowsum3|rowsum4|dots

    hipMemsetAsync(outs, 0, 4 * 16384 + 256, stream);

    norm_kernel<<<2 * NB, 256, 0, stream>>>(M, P, Mf, Pf);
    key_kernel<<<NB / 256, 256, 0, stream>>>(labels, sm, sp, code);
    rowsumw_kernel<<<NB, 256, 0, stream>>>(cs, code, W, flag);

    mega_gemm<<<2064, 256, 0, stream>>>(Mf, Pf, W, outs);

    finalize_kernel<<<1, 256, 0, stream>>>(outs, flag, out);
}